// Round 1
// baseline (1776.459 us; speedup 1.0000x reference)
//
#include <hip/hip_runtime.h>
#include <math.h>

#define NB 8
#define CIN 256
#define SEQ 1024
#define NH 8
#define DH 64
#define HID 512
#define OQKV 1536

// ---------------- K1: qkv[b,o,s] = sum_c w[o,c] * x[b,c,s] ----------------
// grid (16 s-tiles, 48 o-tiles, 8 b), block 256. 32 o per block, 64 s per block.
__global__ __launch_bounds__(256) void qkv_gemm(const float* __restrict__ x,
                                                const float* __restrict__ w,
                                                float* __restrict__ qkv) {
    __shared__ float wl[32 * 256];  // o-major: wl[ol*256 + c]
    const int t = threadIdx.x;
    const int b = blockIdx.z;
    const int ob = blockIdx.y * 32;
    const int sb = blockIdx.x * 64;
    for (int idx = t; idx < 32 * 256; idx += 256)
        wl[idx] = w[(size_t)(ob + (idx >> 8)) * 256 + (idx & 255)];
    __syncthreads();
    const int s = sb + (t & 63);
    const int og = t >> 6;  // 4 groups of 8 o
    const float* xb = x + (size_t)b * CIN * SEQ + s;
    const float* wp = &wl[og * 8 * 256];
    float acc[8] = {0.f, 0.f, 0.f, 0.f, 0.f, 0.f, 0.f, 0.f};
    for (int c = 0; c < 256; ++c) {
        float xv = xb[(size_t)c * SEQ];
#pragma unroll
        for (int k = 0; k < 8; ++k) acc[k] += wp[k * 256 + c] * xv;  // LDS broadcast
    }
#pragma unroll
    for (int k = 0; k < 8; ++k)
        qkv[((size_t)b * OQKV + ob + og * 8 + k) * SEQ + s] = acc[k];
}

// ---------------- K2: in-place RoPE (first 32 of d) + L2 norm along s ------
// grid (48 row-groups, 64 bh, 2 z[q/k]), block 256, 4 s per thread.
__global__ __launch_bounds__(256) void rope_norm(float* __restrict__ qkv) {
    __shared__ float red[512];
    const int t = threadIdx.x;
    const int bh = blockIdx.y;
    const int b = bh >> 3, h = bh & 7;
    const int z = blockIdx.z;  // 0=q, 1=k
    float* base = qkv + ((size_t)b * OQKV + z * HID + h * DH) * SEQ;
    const int g = blockIdx.x;

    if (g < 16) {
        // pair of rotated rows: d = g and d+16
        const int d = g;
        float* r1 = base + (size_t)d * SEQ;
        float* r2 = base + (size_t)(d + 16) * SEQ;
        const float invf = (float)pow(10000.0, -(double)d / 16.0);
        float n1[4], n2[4];
        float ss1 = 0.f, ss2 = 0.f;
#pragma unroll
        for (int r = 0; r < 4; ++r) {
            int s = t + 256 * r;
            float ang = (float)s * invf;  // f32 product, matches reference
            float cs, sn;
            sincosf(ang, &sn, &cs);
            float a1 = r1[s], a2 = r2[s];
            n1[r] = a1 * cs - a2 * sn;
            n2[r] = a2 * cs + a1 * sn;
            ss1 += n1[r] * n1[r];
            ss2 += n2[r] * n2[r];
        }
        red[t] = ss1; red[256 + t] = ss2;
        __syncthreads();
        for (int ofs = 128; ofs > 0; ofs >>= 1) {
            if (t < ofs) { red[t] += red[t + ofs]; red[256 + t] += red[256 + t + ofs]; }
            __syncthreads();
        }
        float inv1 = 1.f / fmaxf(sqrtf(red[0]), 1e-12f);
        float inv2 = 1.f / fmaxf(sqrtf(red[256]), 1e-12f);
#pragma unroll
        for (int r = 0; r < 4; ++r) {
            int s = t + 256 * r;
            r1[s] = n1[r] * inv1;
            r2[s] = n2[r] * inv2;
        }
    } else {
        // unrotated rows d = 32..63: just normalize
        const int d = g + 16;
        float* r1 = base + (size_t)d * SEQ;
        float n1[4];
        float ss = 0.f;
#pragma unroll
        for (int r = 0; r < 4; ++r) {
            int s = t + 256 * r;
            n1[r] = r1[s];
            ss += n1[r] * n1[r];
        }
        red[t] = ss;
        __syncthreads();
        for (int ofs = 128; ofs > 0; ofs >>= 1) {
            if (t < ofs) red[t] += red[t + ofs];
            __syncthreads();
        }
        float inv1 = 1.f / fmaxf(sqrtf(red[0]), 1e-12f);
#pragma unroll
        for (int r = 0; r < 4; ++r) {
            int s = t + 256 * r;
            r1[s] = n1[r] * inv1;
        }
    }
}

// ---------------- K3: attention per (b,h), 8 query rows per block ----------
// grid (128 i-tiles, 64 bh), block 256.
__global__ __launch_bounds__(256) void attn_kernel(const float* __restrict__ qkv,
                                                   float* __restrict__ ao) {
    __shared__ float qls[8 * 64];    // [i][d]
    __shared__ float sc[8 * 1024];   // [i][j] scores -> probs
    const int t = threadIdx.x;
    const int bh = blockIdx.y;
    const int b = bh >> 3, h = bh & 7;
    const int ib = blockIdx.x * 8;
    const float* qb = qkv + ((size_t)b * OQKV + h * DH) * SEQ;
    const float* kb = qkv + ((size_t)b * OQKV + HID + h * DH) * SEQ;
    const float* vb = qkv + ((size_t)b * OQKV + 2 * HID + h * DH) * SEQ;

    for (int idx = t; idx < 512; idx += 256) {
        int d = idx & 63, i = idx >> 6;
        qls[i * 64 + d] = qb[(size_t)d * SEQ + ib + i];
    }
    __syncthreads();

    // phase 1: scores[i][j] = 10 * sum_d q[i][d] k[d][j]
    {
        float acc[4][8];
#pragma unroll
        for (int jc = 0; jc < 4; ++jc)
#pragma unroll
            for (int i = 0; i < 8; ++i) acc[jc][i] = 0.f;
        for (int d = 0; d < 64; ++d) {
            float kv[4];
#pragma unroll
            for (int jc = 0; jc < 4; ++jc) kv[jc] = kb[(size_t)d * SEQ + jc * 256 + t];
#pragma unroll
            for (int i = 0; i < 8; ++i) {
                float qv = qls[i * 64 + d];  // broadcast
#pragma unroll
                for (int jc = 0; jc < 4; ++jc) acc[jc][i] += kv[jc] * qv;
            }
        }
#pragma unroll
        for (int i = 0; i < 8; ++i)
#pragma unroll
            for (int jc = 0; jc < 4; ++jc)
                sc[i * 1024 + jc * 256 + t] = acc[jc][i] * 10.0f;
    }
    __syncthreads();

    // phase 2: softmax per row, wave w handles i = w and w+4
    const int w = t >> 6, lane = t & 63;
#pragma unroll
    for (int rep = 0; rep < 2; ++rep) {
        const int i = w + rep * 4;
        float vreg[16];
        float mx = -1e30f;
#pragma unroll
        for (int m = 0; m < 16; ++m) {
            vreg[m] = sc[i * 1024 + m * 64 + lane];
            mx = fmaxf(mx, vreg[m]);
        }
#pragma unroll
        for (int o = 1; o < 64; o <<= 1) mx = fmaxf(mx, __shfl_xor(mx, o, 64));
        float sm = 0.f;
#pragma unroll
        for (int m = 0; m < 16; ++m) {
            vreg[m] = expf(vreg[m] - mx);
            sm += vreg[m];
        }
#pragma unroll
        for (int o = 1; o < 64; o <<= 1) sm += __shfl_xor(sm, o, 64);
        float r = 1.0f / sm;
#pragma unroll
        for (int m = 0; m < 16; ++m) sc[i * 1024 + m * 64 + lane] = vreg[m] * r;
    }
    __syncthreads();

    // phase 3: out[i][d] = sum_j p[i][j] v[d][j]; wave w owns d in [w*16, w*16+16)
    for (int dc = 0; dc < 4; ++dc) {
        const int d0 = w * 16 + dc * 4;
        float acc[4][8];
#pragma unroll
        for (int dd = 0; dd < 4; ++dd)
#pragma unroll
            for (int i = 0; i < 8; ++i) acc[dd][i] = 0.f;
        for (int m = 0; m < 16; ++m) {
            const int j = m * 64 + lane;
            float p[8];
#pragma unroll
            for (int i = 0; i < 8; ++i) p[i] = sc[i * 1024 + j];
#pragma unroll
            for (int dd = 0; dd < 4; ++dd) {
                float vv = vb[(size_t)(d0 + dd) * SEQ + j];
#pragma unroll
                for (int i = 0; i < 8; ++i) acc[dd][i] += p[i] * vv;
            }
        }
#pragma unroll
        for (int dd = 0; dd < 4; ++dd)
#pragma unroll
            for (int i = 0; i < 8; ++i) {
                float v2 = acc[dd][i];
#pragma unroll
                for (int o = 1; o < 64; o <<= 1) v2 += __shfl_xor(v2, o, 64);
                if (lane == 0)
                    ao[((size_t)b * HID + h * DH + d0 + dd) * SEQ + ib + i] = v2;
            }
    }
}

// ---------------- K4: out[b,o,s] = b_out[o] + sum_c w_out[o,c] * ao[b,c,s] -
// grid (16 s-tiles, 16 o-tiles, 8 b), block 256. 16 o per block.
__global__ __launch_bounds__(256) void out_proj(const float* __restrict__ w_out,
                                                const float* __restrict__ b_out,
                                                const float* __restrict__ ao,
                                                float* __restrict__ out) {
    __shared__ float wl[16 * 512];  // o-major
    const int t = threadIdx.x;
    const int b = blockIdx.z;
    const int ob = blockIdx.y * 16;
    const int sb = blockIdx.x * 64;
    for (int idx = t; idx < 16 * 512; idx += 256)
        wl[idx] = w_out[(size_t)(ob + (idx >> 9)) * 512 + (idx & 511)];
    __syncthreads();
    const int s = sb + (t & 63);
    const int og = t >> 6;  // 4 groups of 4 o
    const float* ab = ao + (size_t)b * HID * SEQ + s;
    float acc[4] = {0.f, 0.f, 0.f, 0.f};
    for (int c = 0; c < 512; ++c) {
        float xv = ab[(size_t)c * SEQ];
#pragma unroll
        for (int k = 0; k < 4; ++k) acc[k] += wl[(og * 4 + k) * 512 + c] * xv;
    }
#pragma unroll
    for (int k = 0; k < 4; ++k) {
        int o = ob + og * 4 + k;
        out[((size_t)b * CIN + o) * SEQ + s] = acc[k] + b_out[o];
    }
}

extern "C" void kernel_launch(void* const* d_in, const int* in_sizes, int n_in,
                              void* d_out, int out_size, void* d_ws, size_t ws_size,
                              hipStream_t stream) {
    const float* x = (const float*)d_in[0];
    const float* w_qkv = (const float*)d_in[1];
    const float* w_out = (const float*)d_in[2];
    const float* b_out = (const float*)d_in[3];
    float* out = (float*)d_out;

    float* qkv = (float*)d_ws;                       // 8*1536*1024 f = 50.3 MB
    float* ao = qkv + (size_t)NB * OQKV * SEQ;       // 8*512*1024 f  = 16.8 MB

    qkv_gemm<<<dim3(16, 48, 8), 256, 0, stream>>>(x, w_qkv, qkv);
    rope_norm<<<dim3(48, 64, 2), 256, 0, stream>>>(qkv);
    attn_kernel<<<dim3(128, 64), 256, 0, stream>>>(qkv, ao);
    out_proj<<<dim3(16, 16, 8), 256, 0, stream>>>(w_out, b_out, ao, out);
}

// Round 2
// 338.221 us; speedup vs baseline: 5.2524x; 5.2524x over previous
//
#include <hip/hip_runtime.h>
#include <math.h>

#define NB 8
#define CIN 256
#define SEQ 1024
#define NH 8
#define DH 64
#define HID 512
#define OQKV 1536

typedef __attribute__((ext_vector_type(8))) short short8;
typedef __attribute__((ext_vector_type(4))) short short4v;
typedef __attribute__((ext_vector_type(4))) float float4v;

static __device__ inline short f2bf(float x) {
    union { float f; unsigned u; } c; c.f = x;
    unsigned r = (c.u + 0x7FFFu + ((c.u >> 16) & 1u)) >> 16;
    return (short)r;
}
static __device__ inline float bf2f(short h) {
    union { unsigned u; float f; } c; c.u = ((unsigned)(unsigned short)h) << 16;
    return c.f;
}

// ---------------- K1: qkv[b,o,s] = sum_c w[o,c] * x[b,c,s] ----------------
__global__ __launch_bounds__(256) void qkv_gemm(const float* __restrict__ x,
                                                const float* __restrict__ w,
                                                float* __restrict__ qkv) {
    __shared__ float wl[32 * 256];  // o-major: wl[ol*256 + c]
    const int t = threadIdx.x;
    const int b = blockIdx.z;
    const int ob = blockIdx.y * 32;
    const int sb = blockIdx.x * 64;
    for (int idx = t; idx < 32 * 256; idx += 256)
        wl[idx] = w[(size_t)(ob + (idx >> 8)) * 256 + (idx & 255)];
    __syncthreads();
    const int s = sb + (t & 63);
    const int og = t >> 6;
    const float* xb = x + (size_t)b * CIN * SEQ + s;
    const float* wp = &wl[og * 8 * 256];
    float acc[8] = {0.f, 0.f, 0.f, 0.f, 0.f, 0.f, 0.f, 0.f};
    for (int c = 0; c < 256; ++c) {
        float xv = xb[(size_t)c * SEQ];
#pragma unroll
        for (int k = 0; k < 8; ++k) acc[k] += wp[k * 256 + c] * xv;
    }
#pragma unroll
    for (int k = 0; k < 8; ++k)
        qkv[((size_t)b * OQKV + ob + og * 8 + k) * SEQ + s] = acc[k];
}

// ---------------- K2: in-place RoPE (first 32 of d) + L2 norm along s ------
__global__ __launch_bounds__(256) void rope_norm(float* __restrict__ qkv) {
    __shared__ float red[512];
    const int t = threadIdx.x;
    const int bh = blockIdx.y;
    const int b = bh >> 3, h = bh & 7;
    const int z = blockIdx.z;
    float* base = qkv + ((size_t)b * OQKV + z * HID + h * DH) * SEQ;
    const int g = blockIdx.x;

    if (g < 16) {
        const int d = g;
        float* r1 = base + (size_t)d * SEQ;
        float* r2 = base + (size_t)(d + 16) * SEQ;
        const float invf = (float)pow(10000.0, -(double)d / 16.0);
        float n1[4], n2[4];
        float ss1 = 0.f, ss2 = 0.f;
#pragma unroll
        for (int r = 0; r < 4; ++r) {
            int s = t + 256 * r;
            float ang = (float)s * invf;
            float cs, sn;
            sincosf(ang, &sn, &cs);
            float a1 = r1[s], a2 = r2[s];
            n1[r] = a1 * cs - a2 * sn;
            n2[r] = a2 * cs + a1 * sn;
            ss1 += n1[r] * n1[r];
            ss2 += n2[r] * n2[r];
        }
        red[t] = ss1; red[256 + t] = ss2;
        __syncthreads();
        for (int ofs = 128; ofs > 0; ofs >>= 1) {
            if (t < ofs) { red[t] += red[t + ofs]; red[256 + t] += red[256 + t + ofs]; }
            __syncthreads();
        }
        float inv1 = 1.f / fmaxf(sqrtf(red[0]), 1e-12f);
        float inv2 = 1.f / fmaxf(sqrtf(red[256]), 1e-12f);
#pragma unroll
        for (int r = 0; r < 4; ++r) {
            int s = t + 256 * r;
            r1[s] = n1[r] * inv1;
            r2[s] = n2[r] * inv2;
        }
    } else {
        const int d = g + 16;
        float* r1 = base + (size_t)d * SEQ;
        float n1[4];
        float ss = 0.f;
#pragma unroll
        for (int r = 0; r < 4; ++r) {
            int s = t + 256 * r;
            n1[r] = r1[s];
            ss += n1[r] * n1[r];
        }
        red[t] = ss;
        __syncthreads();
        for (int ofs = 128; ofs > 0; ofs >>= 1) {
            if (t < ofs) red[t] += red[t + ofs];
            __syncthreads();
        }
        float inv1 = 1.f / fmaxf(sqrtf(red[0]), 1e-12f);
#pragma unroll
        for (int r = 0; r < 4; ++r) {
            int s = t + 256 * r;
            r1[s] = n1[r] * inv1;
        }
    }
}

// ---------------- K3: MFMA attention ---------------------------------------
// Block: 4 waves, 64 query rows (16 per wave). Loop over 32 j-tiles of 32.
// No max-subtraction: scores = 10*(q.k) with q,k unit-norm over s => |S| small,
// exp() safe in fp32; softmax = exp(S)/sum(exp(S)) identical math to ref.
// K/V staged fp32->bf16 into frag-ordered LDS (lane fragment = contiguous 16B).
__global__ __launch_bounds__(256) void attn_mfma(const float* __restrict__ qkv,
                                                 float* __restrict__ ao) {
    __shared__ __align__(16) short kf[2][2][64][8];  // [jhalf][kstep][lane][e]
    __shared__ __align__(16) short vf[4][64][8];     // [dtile][lane][e]
    __shared__ __align__(16) short pt[4][16][72];    // per-wave P tile, pitch 72

    const int t = threadIdx.x;
    const int lane = t & 63, wv = t >> 6;
    const int bh = blockIdx.y, b = bh >> 3, h = bh & 7;
    const int i0 = blockIdx.x * 64;
    const float* qb = qkv + ((size_t)b * OQKV + h * DH) * SEQ;
    const float* kb = qb + (size_t)HID * SEQ;
    const float* vb = qb + (size_t)2 * HID * SEQ;

    // Q A-fragments: A[m=lane&15][k=(lane>>4)*8+e], k-dim = d (2 steps of 32)
    const int iq = i0 + wv * 16 + (lane & 15);
    short8 aq[2];
#pragma unroll
    for (int st = 0; st < 2; ++st)
#pragma unroll
        for (int e = 0; e < 8; ++e) {
            int d = st * 32 + (lane >> 4) * 8 + e;
            aq[st][e] = f2bf(qb[(size_t)d * SEQ + iq]);
        }

    float4v acc[4];  // [dtile]: D[row=(lane>>4)*4+r][col=lane&15]
#pragma unroll
    for (int dt = 0; dt < 4; ++dt) acc[dt] = (float4v){0.f, 0.f, 0.f, 0.f};
    float lsum[4] = {0.f, 0.f, 0.f, 0.f};

    for (int jt = 0; jt < 32; ++jt) {
        __syncthreads();  // prev iteration's LDS reads done before overwrite
        // ---- stage K,V tile (64 d x 32 j) into frag-ordered bf16 LDS ----
#pragma unroll
        for (int p = 0; p < 2; ++p) {
            int n = p * 256 + t;
            int d = n >> 3, jq = n & 7;
            float4v kv = *(const float4v*)(kb + (size_t)d * SEQ + jt * 32 + jq * 4);
#pragma unroll
            for (int c = 0; c < 4; ++c) {
                int jl = jq * 4 + c;
                kf[jl >> 4][d >> 5][((d >> 3) & 3) * 16 + (jl & 15)][d & 7] = f2bf(kv[c]);
            }
            float4v vv = *(const float4v*)(vb + (size_t)d * SEQ + jt * 32 + jq * 4);
            short4v vs;
#pragma unroll
            for (int c = 0; c < 4; ++c) vs[c] = f2bf(vv[c]);
            *(short4v*)&vf[d >> 4][(jq >> 1) * 16 + (d & 15)][(jq & 1) * 4] = vs;
        }
        __syncthreads();

        // ---- scores: two 16x16 tiles (j-halves), contraction over d=64 ----
        short8 bk00 = *(const short8*)&kf[0][0][lane][0];
        short8 bk01 = *(const short8*)&kf[0][1][lane][0];
        short8 bk10 = *(const short8*)&kf[1][0][lane][0];
        short8 bk11 = *(const short8*)&kf[1][1][lane][0];
        float4v s0 = (float4v){0.f, 0.f, 0.f, 0.f};
        float4v s1 = (float4v){0.f, 0.f, 0.f, 0.f};
        s0 = __builtin_amdgcn_mfma_f32_16x16x32_bf16(aq[0], bk00, s0, 0, 0, 0);
        s0 = __builtin_amdgcn_mfma_f32_16x16x32_bf16(aq[1], bk01, s0, 0, 0, 0);
        s1 = __builtin_amdgcn_mfma_f32_16x16x32_bf16(aq[0], bk10, s1, 0, 0, 0);
        s1 = __builtin_amdgcn_mfma_f32_16x16x32_bf16(aq[1], bk11, s1, 0, 0, 0);

        // ---- P = exp(10*S); accumulate row-sum partials; relayout C->A ----
#pragma unroll
        for (int r = 0; r < 4; ++r) {
            float p0 = expf(10.f * s0[r]);
            short pb0 = f2bf(p0);
            lsum[r] += bf2f(pb0);
            pt[wv][(lane >> 4) * 4 + r][lane & 15] = pb0;
            float p1 = expf(10.f * s1[r]);
            short pb1 = f2bf(p1);
            lsum[r] += bf2f(pb1);
            pt[wv][(lane >> 4) * 4 + r][16 + (lane & 15)] = pb1;
        }
        // A-frag of P: contiguous 8 bf16 per lane (wave-private tile)
        short8 ap = *(const short8*)&pt[wv][lane & 15][(lane >> 4) * 8];

        // ---- PV: out[16i x 64d] += P[16x32] * V'[32 x 64] ----
#pragma unroll
        for (int dt = 0; dt < 4; ++dt) {
            short8 bv = *(const short8*)&vf[dt][lane][0];
            acc[dt] = __builtin_amdgcn_mfma_f32_16x16x32_bf16(ap, bv, acc[dt], 0, 0, 0);
        }
    }

    // reduce row-sums across the 16 lanes holding each row's columns
#pragma unroll
    for (int r = 0; r < 4; ++r) {
        float v = lsum[r];
#pragma unroll
        for (int o = 1; o < 16; o <<= 1) v += __shfl_xor(v, o, 64);
        lsum[r] = v;
    }

    float* aob = ao + ((size_t)b * HID + h * DH) * SEQ;
#pragma unroll
    for (int dt = 0; dt < 4; ++dt)
#pragma unroll
        for (int r = 0; r < 4; ++r) {
            int d = dt * 16 + (lane & 15);
            int s = i0 + wv * 16 + (lane >> 4) * 4 + r;
            aob[(size_t)d * SEQ + s] = acc[dt][r] / lsum[r];
        }
}

// ---------------- K4: out[b,o,s] = b_out[o] + sum_c w_out[o,c] * ao[b,c,s] -
__global__ __launch_bounds__(256) void out_proj(const float* __restrict__ w_out,
                                                const float* __restrict__ b_out,
                                                const float* __restrict__ ao,
                                                float* __restrict__ out) {
    __shared__ float wl[16 * 512];
    const int t = threadIdx.x;
    const int b = blockIdx.z;
    const int ob = blockIdx.y * 16;
    const int sb = blockIdx.x * 64;
    for (int idx = t; idx < 16 * 512; idx += 256)
        wl[idx] = w_out[(size_t)(ob + (idx >> 9)) * 512 + (idx & 511)];
    __syncthreads();
    const int s = sb + (t & 63);
    const int og = t >> 6;
    const float* ab = ao + (size_t)b * HID * SEQ + s;
    float acc[4] = {0.f, 0.f, 0.f, 0.f};
    for (int c = 0; c < 512; ++c) {
        float xv = ab[(size_t)c * SEQ];
#pragma unroll
        for (int k = 0; k < 4; ++k) acc[k] += wl[(og * 4 + k) * 512 + c] * xv;
    }
#pragma unroll
    for (int k = 0; k < 4; ++k) {
        int o = ob + og * 4 + k;
        out[((size_t)b * CIN + o) * SEQ + s] = acc[k] + b_out[o];
    }
}

extern "C" void kernel_launch(void* const* d_in, const int* in_sizes, int n_in,
                              void* d_out, int out_size, void* d_ws, size_t ws_size,
                              hipStream_t stream) {
    const float* x = (const float*)d_in[0];
    const float* w_qkv = (const float*)d_in[1];
    const float* w_out = (const float*)d_in[2];
    const float* b_out = (const float*)d_in[3];
    float* out = (float*)d_out;

    float* qkv = (float*)d_ws;                   // 8*1536*1024 f = 50.3 MB
    float* ao = qkv + (size_t)NB * OQKV * SEQ;   // 8*512*1024 f  = 16.8 MB

    qkv_gemm<<<dim3(16, 48, 8), 256, 0, stream>>>(x, w_qkv, qkv);
    rope_norm<<<dim3(48, 64, 2), 256, 0, stream>>>(qkv);
    attn_mfma<<<dim3(16, 64), 256, 0, stream>>>(qkv, ao);
    out_proj<<<dim3(16, 16, 8), 256, 0, stream>>>(w_out, b_out, ao, out);
}

// Round 3
// 232.650 us; speedup vs baseline: 7.6358x; 1.4538x over previous
//
#include <hip/hip_runtime.h>
#include <math.h>

#define NB 8
#define CIN 256
#define SEQ 1024
#define NH 8
#define DH 64
#define HID 512
#define OQKV 1536

typedef __attribute__((ext_vector_type(8))) short short8;
typedef __attribute__((ext_vector_type(4))) short short4v;
typedef __attribute__((ext_vector_type(4))) float float4v;

static __device__ inline short f2bf(float x) {
    union { float f; unsigned u; } c; c.f = x;
    unsigned r = (c.u + 0x7FFFu + ((c.u >> 16) & 1u)) >> 16;
    return (short)r;
}
static __device__ inline float bf2f(short h) {
    union { unsigned u; float f; } c; c.u = ((unsigned)(unsigned short)h) << 16;
    return c.f;
}

// ============ MFMA GEMM: C[b,m,n] = sum_k A[m,k] * B[b,k,n] (+ bias[m]) =====
// A: weights [M][K] row-major (k contiguous). B: activations, n contiguous.
// BN=128, BK=32. LDS pitch 36 shorts (72B): 8B-aligned for ds_read_b64 pairs,
// odd-ish word stride keeps dense-lane staging stores at ~4-way (1.58x, ~free).
#define BN 128
#define BK 32
#define LP 36

template<int BM, int WAVES_M, int WM, int WN, bool BIAS>
__global__ __launch_bounds__(256) void gemm_mfma(const float* __restrict__ A,
                                                 const float* __restrict__ B,
                                                 const float* __restrict__ bias,
                                                 float* __restrict__ C,
                                                 int M, int K) {
    __shared__ __align__(16) short As[BM * LP];
    __shared__ __align__(16) short Bs[BN * LP];
    const int t = threadIdx.x;
    const int lane = t & 63, wv = t >> 6;
    const int b = blockIdx.z;
    const int m0 = blockIdx.y * BM;
    const int n0 = blockIdx.x * BN;
    const int wvm = (wv % WAVES_M) * WM * 16;
    const int wvn = (wv / WAVES_M) * WN * 16;

    const float* Ab = A + (size_t)m0 * K;
    const float* Bb = B + (size_t)b * K * SEQ + n0;

    float4v acc[WM][WN];
#pragma unroll
    for (int i = 0; i < WM; ++i)
#pragma unroll
        for (int j = 0; j < WN; ++j) acc[i][j] = (float4v){0.f, 0.f, 0.f, 0.f};

    for (int k0 = 0; k0 < K; k0 += BK) {
        __syncthreads();
        // ---- stage A tile: BM x 32 (float4 along k, coalesced) ----
#pragma unroll
        for (int q = t; q < BM * 8; q += 256) {
            int m = q >> 3, kq = (q & 7) * 4;
            float4v v = *(const float4v*)(Ab + (size_t)m * K + k0 + kq);
            short4v s4;
#pragma unroll
            for (int c = 0; c < 4; ++c) s4[c] = f2bf(v[c]);
            *(short4v*)&As[m * LP + kq] = s4;
        }
        // ---- stage B tile: 32 x 128 (scalar loads coalesced along n) ----
#pragma unroll
        for (int q = t; q < BN * 8; q += 256) {
            int n = q & (BN - 1), kq = (q >> 7) * 4;
            short4v s4;
#pragma unroll
            for (int c = 0; c < 4; ++c)
                s4[c] = f2bf(Bb[(size_t)(k0 + kq + c) * SEQ + n]);
            *(short4v*)&Bs[n * LP + kq] = s4;
        }
        __syncthreads();

        const int koff = (lane >> 4) * 8;
        short8 af[WM], bfr[WN];
#pragma unroll
        for (int i = 0; i < WM; ++i) {
            int m = wvm + i * 16 + (lane & 15);
            short4v lo = *(const short4v*)&As[m * LP + koff];
            short4v hi = *(const short4v*)&As[m * LP + koff + 4];
            af[i] = (short8){lo[0], lo[1], lo[2], lo[3], hi[0], hi[1], hi[2], hi[3]};
        }
#pragma unroll
        for (int j = 0; j < WN; ++j) {
            int n = wvn + j * 16 + (lane & 15);
            short4v lo = *(const short4v*)&Bs[n * LP + koff];
            short4v hi = *(const short4v*)&Bs[n * LP + koff + 4];
            bfr[j] = (short8){lo[0], lo[1], lo[2], lo[3], hi[0], hi[1], hi[2], hi[3]};
        }
#pragma unroll
        for (int i = 0; i < WM; ++i)
#pragma unroll
            for (int j = 0; j < WN; ++j)
                acc[i][j] = __builtin_amdgcn_mfma_f32_16x16x32_bf16(af[i], bfr[j],
                                                                    acc[i][j], 0, 0, 0);
    }

#pragma unroll
    for (int i = 0; i < WM; ++i)
#pragma unroll
        for (int r = 0; r < 4; ++r) {
            int m = m0 + wvm + i * 16 + (lane >> 4) * 4 + r;
            float bv = BIAS ? bias[m] : 0.f;
#pragma unroll
            for (int j = 0; j < WN; ++j) {
                int n = n0 + wvn + j * 16 + (lane & 15);
                C[((size_t)b * M + m) * SEQ + n] = acc[i][j][r] + bv;
            }
        }
}

// ---------------- K2: in-place RoPE (first 32 of d) + L2 norm along s ------
__global__ __launch_bounds__(256) void rope_norm(float* __restrict__ qkv) {
    __shared__ float red[512];
    const int t = threadIdx.x;
    const int bh = blockIdx.y;
    const int b = bh >> 3, h = bh & 7;
    const int z = blockIdx.z;
    float* base = qkv + ((size_t)b * OQKV + z * HID + h * DH) * SEQ;
    const int g = blockIdx.x;

    if (g < 16) {
        const int d = g;
        float* r1 = base + (size_t)d * SEQ;
        float* r2 = base + (size_t)(d + 16) * SEQ;
        const float invf = (float)pow(10000.0, -(double)d / 16.0);
        float n1[4], n2[4];
        float ss1 = 0.f, ss2 = 0.f;
#pragma unroll
        for (int r = 0; r < 4; ++r) {
            int s = t + 256 * r;
            float ang = (float)s * invf;
            float cs, sn;
            sincosf(ang, &sn, &cs);
            float a1 = r1[s], a2 = r2[s];
            n1[r] = a1 * cs - a2 * sn;
            n2[r] = a2 * cs + a1 * sn;
            ss1 += n1[r] * n1[r];
            ss2 += n2[r] * n2[r];
        }
        red[t] = ss1; red[256 + t] = ss2;
        __syncthreads();
        for (int ofs = 128; ofs > 0; ofs >>= 1) {
            if (t < ofs) { red[t] += red[t + ofs]; red[256 + t] += red[256 + t + ofs]; }
            __syncthreads();
        }
        float inv1 = 1.f / fmaxf(sqrtf(red[0]), 1e-12f);
        float inv2 = 1.f / fmaxf(sqrtf(red[256]), 1e-12f);
#pragma unroll
        for (int r = 0; r < 4; ++r) {
            int s = t + 256 * r;
            r1[s] = n1[r] * inv1;
            r2[s] = n2[r] * inv2;
        }
    } else {
        const int d = g + 16;
        float* r1 = base + (size_t)d * SEQ;
        float n1[4];
        float ss = 0.f;
#pragma unroll
        for (int r = 0; r < 4; ++r) {
            int s = t + 256 * r;
            n1[r] = r1[s];
            ss += n1[r] * n1[r];
        }
        red[t] = ss;
        __syncthreads();
        for (int ofs = 128; ofs > 0; ofs >>= 1) {
            if (t < ofs) red[t] += red[t + ofs];
            __syncthreads();
        }
        float inv1 = 1.f / fmaxf(sqrtf(red[0]), 1e-12f);
#pragma unroll
        for (int r = 0; r < 4; ++r) {
            int s = t + 256 * r;
            r1[s] = n1[r] * inv1;
        }
    }
}

// ---------------- K3: MFMA attention ---------------------------------------
__global__ __launch_bounds__(256) void attn_mfma(const float* __restrict__ qkv,
                                                 float* __restrict__ ao) {
    __shared__ __align__(16) short kf[2][2][64][8];  // [jhalf][kstep][lane][e]
    __shared__ __align__(16) short vf[4][64][8];     // [dtile][lane][e]
    __shared__ __align__(16) short pt[4][16][72];    // per-wave P tile, pitch 72

    const int t = threadIdx.x;
    const int lane = t & 63, wv = t >> 6;
    const int bh = blockIdx.y, b = bh >> 3, h = bh & 7;
    const int i0 = blockIdx.x * 64;
    const float* qb = qkv + ((size_t)b * OQKV + h * DH) * SEQ;
    const float* kb = qb + (size_t)HID * SEQ;
    const float* vb = qb + (size_t)2 * HID * SEQ;

    const int iq = i0 + wv * 16 + (lane & 15);
    short8 aq[2];
#pragma unroll
    for (int st = 0; st < 2; ++st)
#pragma unroll
        for (int e = 0; e < 8; ++e) {
            int d = st * 32 + (lane >> 4) * 8 + e;
            aq[st][e] = f2bf(qb[(size_t)d * SEQ + iq]);
        }

    float4v acc[4];
#pragma unroll
    for (int dt = 0; dt < 4; ++dt) acc[dt] = (float4v){0.f, 0.f, 0.f, 0.f};
    float lsum[4] = {0.f, 0.f, 0.f, 0.f};

    for (int jt = 0; jt < 32; ++jt) {
        __syncthreads();
#pragma unroll
        for (int p = 0; p < 2; ++p) {
            int n = p * 256 + t;
            int d = n >> 3, jq = n & 7;
            float4v kv = *(const float4v*)(kb + (size_t)d * SEQ + jt * 32 + jq * 4);
#pragma unroll
            for (int c = 0; c < 4; ++c) {
                int jl = jq * 4 + c;
                kf[jl >> 4][d >> 5][((d >> 3) & 3) * 16 + (jl & 15)][d & 7] = f2bf(kv[c]);
            }
            float4v vv = *(const float4v*)(vb + (size_t)d * SEQ + jt * 32 + jq * 4);
            short4v vs;
#pragma unroll
            for (int c = 0; c < 4; ++c) vs[c] = f2bf(vv[c]);
            *(short4v*)&vf[d >> 4][(jq >> 1) * 16 + (d & 15)][(jq & 1) * 4] = vs;
        }
        __syncthreads();

        short8 bk00 = *(const short8*)&kf[0][0][lane][0];
        short8 bk01 = *(const short8*)&kf[0][1][lane][0];
        short8 bk10 = *(const short8*)&kf[1][0][lane][0];
        short8 bk11 = *(const short8*)&kf[1][1][lane][0];
        float4v s0 = (float4v){0.f, 0.f, 0.f, 0.f};
        float4v s1 = (float4v){0.f, 0.f, 0.f, 0.f};
        s0 = __builtin_amdgcn_mfma_f32_16x16x32_bf16(aq[0], bk00, s0, 0, 0, 0);
        s0 = __builtin_amdgcn_mfma_f32_16x16x32_bf16(aq[1], bk01, s0, 0, 0, 0);
        s1 = __builtin_amdgcn_mfma_f32_16x16x32_bf16(aq[0], bk10, s1, 0, 0, 0);
        s1 = __builtin_amdgcn_mfma_f32_16x16x32_bf16(aq[1], bk11, s1, 0, 0, 0);

#pragma unroll
        for (int r = 0; r < 4; ++r) {
            float p0 = expf(10.f * s0[r]);
            short pb0 = f2bf(p0);
            lsum[r] += bf2f(pb0);
            pt[wv][(lane >> 4) * 4 + r][lane & 15] = pb0;
            float p1 = expf(10.f * s1[r]);
            short pb1 = f2bf(p1);
            lsum[r] += bf2f(pb1);
            pt[wv][(lane >> 4) * 4 + r][16 + (lane & 15)] = pb1;
        }
        short8 ap = *(const short8*)&pt[wv][lane & 15][(lane >> 4) * 8];

#pragma unroll
        for (int dt = 0; dt < 4; ++dt) {
            short8 bv = *(const short8*)&vf[dt][lane][0];
            acc[dt] = __builtin_amdgcn_mfma_f32_16x16x32_bf16(ap, bv, acc[dt], 0, 0, 0);
        }
    }

#pragma unroll
    for (int r = 0; r < 4; ++r) {
        float v = lsum[r];
#pragma unroll
        for (int o = 1; o < 16; o <<= 1) v += __shfl_xor(v, o, 64);
        lsum[r] = v;
    }

    float* aob = ao + ((size_t)b * HID + h * DH) * SEQ;
#pragma unroll
    for (int dt = 0; dt < 4; ++dt)
#pragma unroll
        for (int r = 0; r < 4; ++r) {
            int d = dt * 16 + (lane & 15);
            int s = i0 + wv * 16 + (lane >> 4) * 4 + r;
            aob[(size_t)d * SEQ + s] = acc[dt][r] / lsum[r];
        }
}

extern "C" void kernel_launch(void* const* d_in, const int* in_sizes, int n_in,
                              void* d_out, int out_size, void* d_ws, size_t ws_size,
                              hipStream_t stream) {
    const float* x = (const float*)d_in[0];
    const float* w_qkv = (const float*)d_in[1];
    const float* w_out = (const float*)d_in[2];
    const float* b_out = (const float*)d_in[3];
    float* out = (float*)d_out;

    float* qkv = (float*)d_ws;                   // 8*1536*1024 f = 50.3 MB
    float* ao = qkv + (size_t)NB * OQKV * SEQ;   // 8*512*1024 f  = 16.8 MB

    // qkv: M=1536, K=256; 128x128 tiles, 2x2 waves of 4x4 frags
    gemm_mfma<128, 2, 4, 4, false><<<dim3(8, 12, 8), 256, 0, stream>>>(
        w_qkv, x, nullptr, qkv, OQKV, CIN);
    rope_norm<<<dim3(48, 64, 2), 256, 0, stream>>>(qkv);
    attn_mfma<<<dim3(16, 64), 256, 0, stream>>>(qkv, ao);
    // out: M=256, K=512; 64x128 tiles, 1x4 waves of 4x2 frags
    gemm_mfma<64, 1, 4, 2, true><<<dim3(8, 4, 8), 256, 0, stream>>>(
        w_out, ao, b_out, out, CIN, HID);
}